// Round 3
// baseline (303.549 us; speedup 1.0000x reference)
//
#include <hip/hip_runtime.h>
#include <math.h>

#define WID 512
#define NB  32
#define NC  3
#define WW  (WID * WID)

constexpr float SCALE_F   = (float)(4.0 / 511.0);
constexpr float DEF_OFF_F = (float)((2.0 + 4.0 / 511.0) * 0.5);
constexpr float CLIP_F    = 0.03125f; // PIX_W*EPS -> max displacement 7.984 px

__device__ __forceinline__ int refl(int r) {
  r = r < 0 ? -r : r;
  return r > WID - 1 ? 2 * (WID - 1) - r : r;
}

__device__ __forceinline__ float seqf(int i) {
  return ((float)(2 * i - 511)) / 511.0f;
}

// ---------------- merged grid kernel: kx (blocks 0..2047) + ky1 (2048..3071) --
#define KY1_ROWS 133
#define KY1_COLS 72

__global__ __launch_bounds__(512)
void grid_kernel(const float* __restrict__ pg, float* __restrict__ gridx,
                 float* __restrict__ gridy, float* __restrict__ qsum,
                 float kw0, float kw1, float kw2) {
  if (blockIdx.x < 2048) {
    // ================= x-channel: wave-per-row, no LDS, no barriers ==========
    const int lane = threadIdx.x & 63;
    const int wv   = threadIdx.x >> 6;
    const int R = blockIdx.x * 8 + wv;
    const int b = R >> 9;
    const int i = R & (WID - 1);
    const float* base = pg + (size_t)b * 2 * WW;

    float v[8] = {0.f,0.f,0.f,0.f,0.f,0.f,0.f,0.f};
    const int rows[5] = {refl(i - 2), refl(i - 1), i, refl(i + 1), refl(i + 2)};
    const float wts[5] = {kw0, kw1, kw2, kw1, kw0};
#pragma unroll
    for (int r = 0; r < 5; ++r) {
      const float4* p = (const float4*)(base + (size_t)rows[r] * WID + lane * 8);
      float4 A = p[0], Bq = p[1];
      float w = wts[r];
      v[0] += w * A.x;  v[1] += w * A.y;  v[2] += w * A.z;  v[3] += w * A.w;
      v[4] += w * Bq.x; v[5] += w * Bq.y; v[6] += w * Bq.z; v[7] += w * Bq.w;
    }

    float em1 = __shfl_up(v[7], 1, 64);
    float em2 = __shfl_up(v[6], 1, 64);
    float ep8 = __shfl_down(v[0], 1, 64);
    float ep9 = __shfl_down(v[1], 1, 64);
    if (lane == 0)  { em1 = v[1]; em2 = v[2]; }
    if (lane == 63) { ep8 = v[6]; ep9 = v[5]; }

    float h[8];
    h[0] = kw2 * v[0] + kw1 * (em1 + v[1]) + kw0 * (em2 + v[2]);
    h[1] = kw2 * v[1] + kw1 * (v[0] + v[2]) + kw0 * (em1 + v[3]);
#pragma unroll
    for (int k = 2; k < 6; ++k)
      h[k] = kw2 * v[k] + kw1 * (v[k - 1] + v[k + 1]) + kw0 * (v[k - 2] + v[k + 2]);
    h[6] = kw2 * v[6] + kw1 * (v[5] + v[7]) + kw0 * (v[4] + ep8);
    h[7] = kw2 * v[7] + kw1 * (v[6] + ep8) + kw0 * (v[5] + ep9);

    float s[8], a[8], p[8];
#pragma unroll
    for (int k = 0; k < 8; ++k) s[k] = h[k] + seqf(lane * 8 + k) + DEF_OFF_F;

    float sm1 = __shfl_up(s[7], 1, 64);
    if (lane == 0) sm1 = 0.0f;
    a[0] = fmaxf((s[0] - sm1) / SCALE_F, 0.0f) * SCALE_F;
#pragma unroll
    for (int k = 1; k < 8; ++k)
      a[k] = fmaxf((s[k] - s[k - 1]) / SCALE_F, 0.0f) * SCALE_F;

    p[0] = a[0];
#pragma unroll
    for (int k = 1; k < 8; ++k) p[k] = p[k - 1] + a[k];
    float incl = p[7];
#pragma unroll
    for (int off = 1; off < 64; off <<= 1) {
      float n = __shfl_up(incl, off, 64);
      if (lane >= off) incl += n;
    }
    float excl = incl - p[7];

    float og[8];
#pragma unroll
    for (int k = 0; k < 8; ++k) {
      float gx = seqf(lane * 8 + k);
      float d = (p[k] + excl) - DEF_OFF_F - gx;
      d = fminf(fmaxf(d, -CLIP_F), CLIP_F);
      og[k] = fminf(fmaxf(d + gx, -1.0f), 1.0f);
    }
    float4* o = (float4*)(gridx + ((size_t)b * WID + i) * WID + lane * 8);
    o[0] = make_float4(og[0], og[1], og[2], og[3]);
    o[1] = make_float4(og[4], og[5], og[6], og[7]);
  } else {
    // ================= y-channel pass 1: 128 rows x 64 cols, 8 segs x 16 =====
    const int bid  = blockIdx.x - 2048;
    const int q    = bid & 3;        // row-quad 0..3 (128 rows each)
    const int tile = (bid >> 2) & 7; // col-tile 0..7 (64 cols each)
    const int b    = bid >> 5;
    const int q0   = q << 7;
    const int gc0  = tile << 6;

    __shared__ float L[KY1_ROWS * KY1_COLS]; // 38.3 KB
    __shared__ float ss[8][64];

    const float* src = pg + ((size_t)b * 2 + 1) * WW;
    for (int idx = threadIdx.x; idx < KY1_ROWS * 18; idx += 512) {
      int lr = idx / 18;
      int k  = idx - lr * 18;
      int gr = refl(q0 - 3 + lr);
      int gcb = gc0 - 4 + (k << 2);
      gcb = gcb < 0 ? 0 : (gcb > WID - 4 ? WID - 4 : gcb);
      float4 v = *(const float4*)(src + (size_t)gr * WID + gcb);
      *(float4*)(&L[lr * KY1_COLS + (k << 2)]) = v;
    }
    __syncthreads();

    const int j   = threadIdx.x & 63;
    const int seg = threadIdx.x >> 6;       // 16-row segment within quad

    int jcc[5];
#pragma unroll
    for (int d = 0; d < 5; ++d)
      jcc[d] = refl(gc0 + j + d - 2) - gc0 + 4; // always in [0,71]

    auto HB = [&](int r) -> float {
      const float* Lr = &L[r * KY1_COLS];
      return kw2 * Lr[jcc[2]] + kw1 * (Lr[jcc[1]] + Lr[jcc[3]])
           + kw0 * (Lr[jcc[0]] + Lr[jcc[4]]);
    };

    const int lri0 = seg * 16 + 2;          // lds row of istart
    float hm2 = HB(lri0 - 2);
    float hm1 = HB(lri0 - 1);
    float hc  = HB(lri0);
    float hp1 = HB(lri0 + 1);
    float hp2 = HB(lri0 + 2);

    const int istart = q0 + seg * 16 - 1;
    float areg[16];
    float sprev = 0.0f, suma = 0.0f;
#pragma unroll
    for (int k = 0; k <= 16; ++k) {
      float blur = kw2 * hc + kw1 * (hm1 + hp1) + kw0 * (hm2 + hp2);
      float s = blur + seqf(istart + k) + DEF_OFF_F;
      if (k == 0) {
        sprev = (q == 0 && seg == 0) ? 0.0f : s;
      } else {
        float a = fmaxf((s - sprev) / SCALE_F, 0.0f) * SCALE_F;
        areg[k - 1] = a;
        suma += a;
        sprev = s;
      }
      if (k < 16) {
        hm2 = hm1; hm1 = hc; hc = hp1; hp1 = hp2;
        hp2 = HB(lri0 + k + 3);
      }
    }

    ss[seg][j] = suma;
    __syncthreads();
    float off = 0.0f;
#pragma unroll
    for (int w = 0; w < 7; ++w)
      if (w < seg) off += ss[w][j];
    if (seg == 7)
      qsum[((size_t)b * 4 + q) * WID + gc0 + j] = off + suma;

    float* ob = gridy + (size_t)b * WW + (size_t)(q0 + seg * 16) * WID + gc0 + j;
    float cum = off;
#pragma unroll
    for (int k = 0; k < 16; ++k) {
      cum += areg[k];
      ob[(size_t)k * WID] = cum;  // partial cumsum; finalized in sample (fused)
    }
  }
}

// ---------------- y-channel pass 2 (fallback only, if qsum must live in out) --
__global__ __launch_bounds__(128)
void ky2_kernel(float* __restrict__ gridy, const float* __restrict__ qsum) {
  const int b = blockIdx.x >> 9;
  const int i = blockIdx.x & 511;
  const int q = i >> 7;
  const int j4 = threadIdx.x << 2;
  const float* qs = qsum + (size_t)b * 4 * WID + j4;
  float ox = 0.f, oy = 0.f, oz = 0.f, ow = 0.f;
  for (int w = 0; w < q; ++w) {
    float4 t = *(const float4*)(qs + (size_t)w * WID);
    ox += t.x; oy += t.y; oz += t.z; ow += t.w;
  }
  const float gy = seqf(i);
  float* p = gridy + ((size_t)b * WID + i) * WID + j4;
  float4 v = *(float4*)p;
  auto fin = [&](float c) -> float {
    float d = c - DEF_OFF_F - gy;
    d = fminf(fmaxf(d, -CLIP_F), CLIP_F);
    return fminf(fmaxf(d + gy, -1.0f), 1.0f);
  };
  v.x = fin(v.x + ox); v.y = fin(v.y + oy);
  v.z = fin(v.z + oz); v.w = fin(v.w + ow);
  *(float4*)p = v;
}

// ---------------- direct-gather bilinear sample (no LDS, no barriers) --------
// Displacement <= 7.984 px: a wave's 4 taps touch ~2-3 image rows x ~5 cache
// lines -> L1/L2 serve the reuse; XCD swizzle keeps adjacent row-tiles
// (sharing halo rows) on the same XCD's L2. gx,gy in [-1,1] => x,y in
// [0,511]: only the +1 taps can exceed 511 and their bilinear weight is then
// exactly 0, so clamped offsets (dx,dy) replace the valid-mask mults.
#define STILE  8
#define SAMP_BLOCKS (NB * NC * (WID / STILE))  // 6144

template<bool FUSEY>
__global__ __launch_bounds__(512)
void sample_kernel(const float* __restrict__ img, const float* __restrict__ gridx,
                   const float* __restrict__ gridy, const float* __restrict__ qsum,
                   float* __restrict__ out) {
  const int nb = (blockIdx.x & 7) * (SAMP_BLOCKS / 8) + (blockIdx.x >> 3);
  const int rt = nb & 63;            // 64 row-tiles
  const int bc = nb >> 6;            // b*3 + c
  const int b  = bc / 3;
  const int c  = bc - b * 3;
  const int r0 = rt * STILE;
  const int j  = threadIdx.x;

  const float* ic = img + ((size_t)b * NC + c) * WW;
  float* ob = out + ((size_t)b * NC + c) * WW;

  // cross-quad y-offset: uniform quad per block (128 % STILE == 0)
  float offy = 0.0f;
  if (FUSEY) {
    const int q = r0 >> 7;
    const float* qs = qsum + (size_t)b * 4 * WID + j;
    for (int w = 0; w < q; ++w) offy += qs[(size_t)w * WID];
  }

#pragma unroll
  for (int r = 0; r < STILE; ++r) {
    const int i = r0 + r;
    const size_t gidx = ((size_t)b * WID + i) * WID + j;
    float gx = gridx[gidx];
    float gy = gridy[gidx];
    if (FUSEY) {
      const float gyl = seqf(i);
      float d = (gy + offy) - DEF_OFF_F - gyl;
      d = fminf(fmaxf(d, -CLIP_F), CLIP_F);
      gy = fminf(fmaxf(d + gyl, -1.0f), 1.0f);
    }
    float x = (gx + 1.0f) * (0.5f * (float)(WID - 1));
    float y = (gy + 1.0f) * (0.5f * (float)(WID - 1));
    float x0f = floorf(x), y0f = floorf(y);
    int x0 = (int)x0f, y0 = (int)y0f;
    float wx1 = x - x0f, wx0 = 1.0f - wx1;
    float wy1 = y - y0f, wy0 = 1.0f - wy1;

    int dx = x0 < WID - 1 ? 1 : 0;      // +1 tap weight is exactly 0 when clamped
    int dy = y0 < WID - 1 ? WID : 0;
    int idx = (y0 << 9) + x0;

    float v00 = ic[idx];
    float v01 = ic[idx + dx];
    float v10 = ic[idx + dy];
    float v11 = ic[idx + dy + dx];

    ob[(size_t)i * WID + j] =
        wy0 * (wx0 * v00 + wx1 * v01) + wy1 * (wx0 * v10 + wx1 * v11);
  }
}

extern "C" void kernel_launch(void* const* d_in, const int* in_sizes, int n_in,
                              void* d_out, int out_size, void* d_ws, size_t ws_size,
                              hipStream_t stream) {
  const float* img = (const float*)d_in[0];
  const float* pg  = (const float*)d_in[1];
  float* out = (float*)d_out;

  float* gridx = (float*)d_ws;
  float* gridy = gridx + (size_t)NB * WW;

  const size_t grids_bytes = (size_t)2 * NB * WW * sizeof(float);
  const size_t qsum_bytes  = (size_t)NB * 4 * WID * sizeof(float); // 256 KB
  const bool ws_fits = (ws_size >= grids_bytes + qsum_bytes);
  float* qsum = ws_fits ? (float*)((char*)d_ws + grids_bytes)
                        : (float*)d_out;  // fallback scratch; needs ky2 pass

  double sigma = 5.0 * 0.15 + 0.35;
  double p0 = exp(-0.5 * (2.0 / sigma) * (2.0 / sigma));
  double p1 = exp(-0.5 * (1.0 / sigma) * (1.0 / sigma));
  double p2 = 1.0;
  double sum = 2.0 * p0 + 2.0 * p1 + p2;
  float kw0 = (float)(p0 / sum), kw1 = (float)(p1 / sum), kw2 = (float)(p2 / sum);

  grid_kernel<<<2048 + NB * 32, 512, 0, stream>>>(pg, gridx, gridy, qsum,
                                                  kw0, kw1, kw2);
  if (ws_fits) {
    sample_kernel<true><<<SAMP_BLOCKS, 512, 0, stream>>>(img, gridx, gridy,
                                                         qsum, out);
  } else {
    ky2_kernel<<<NB * WID, 128, 0, stream>>>(gridy, qsum);
    sample_kernel<false><<<SAMP_BLOCKS, 512, 0, stream>>>(img, gridx, gridy,
                                                          qsum, out);
  }
}

// Round 4
// 260.995 us; speedup vs baseline: 1.1630x; 1.1630x over previous
//
#include <hip/hip_runtime.h>
#include <math.h>

#define WID 512
#define NB  32
#define NC  3
#define WW  (WID * WID)

constexpr float SCALE_F   = (float)(4.0 / 511.0);
constexpr float DEF_OFF_F = (float)((2.0 + 4.0 / 511.0) * 0.5);
constexpr float CLIP_F    = 0.03125f; // PIX_W*EPS -> max displacement 7.984 px

__device__ __forceinline__ int refl(int r) {
  r = r < 0 ? -r : r;
  return r > WID - 1 ? 2 * (WID - 1) - r : r;
}

__device__ __forceinline__ float seqf(int i) {
  return ((float)(2 * i - 511)) / 511.0f;
}

__device__ __forceinline__ void gl_lds16(const float* g, float* l) {
  __builtin_amdgcn_global_load_lds(
      (const __attribute__((address_space(1))) void*)g,
      (__attribute__((address_space(3))) void*)l, 16, 0, 0);
}

// ---------------- merged grid kernel: kx (blocks 0..2047) + ky1 (2048..3071) --
#define KY1_ROWS 133
#define KY1_COLS 72

__global__ __launch_bounds__(512)
void grid_kernel(const float* __restrict__ pg, float* __restrict__ gridx,
                 float* __restrict__ gridy, float* __restrict__ qsum,
                 float kw0, float kw1, float kw2) {
  if (blockIdx.x < 2048) {
    // ================= x-channel: wave-per-row, no LDS, no barriers ==========
    const int lane = threadIdx.x & 63;
    const int wv   = threadIdx.x >> 6;
    const int R = blockIdx.x * 8 + wv;
    const int b = R >> 9;
    const int i = R & (WID - 1);
    const float* base = pg + (size_t)b * 2 * WW;

    float v[8] = {0.f,0.f,0.f,0.f,0.f,0.f,0.f,0.f};
    const int rows[5] = {refl(i - 2), refl(i - 1), i, refl(i + 1), refl(i + 2)};
    const float wts[5] = {kw0, kw1, kw2, kw1, kw0};
#pragma unroll
    for (int r = 0; r < 5; ++r) {
      const float4* p = (const float4*)(base + (size_t)rows[r] * WID + lane * 8);
      float4 A = p[0], Bq = p[1];
      float w = wts[r];
      v[0] += w * A.x;  v[1] += w * A.y;  v[2] += w * A.z;  v[3] += w * A.w;
      v[4] += w * Bq.x; v[5] += w * Bq.y; v[6] += w * Bq.z; v[7] += w * Bq.w;
    }

    float em1 = __shfl_up(v[7], 1, 64);
    float em2 = __shfl_up(v[6], 1, 64);
    float ep8 = __shfl_down(v[0], 1, 64);
    float ep9 = __shfl_down(v[1], 1, 64);
    if (lane == 0)  { em1 = v[1]; em2 = v[2]; }
    if (lane == 63) { ep8 = v[6]; ep9 = v[5]; }

    float h[8];
    h[0] = kw2 * v[0] + kw1 * (em1 + v[1]) + kw0 * (em2 + v[2]);
    h[1] = kw2 * v[1] + kw1 * (v[0] + v[2]) + kw0 * (em1 + v[3]);
#pragma unroll
    for (int k = 2; k < 6; ++k)
      h[k] = kw2 * v[k] + kw1 * (v[k - 1] + v[k + 1]) + kw0 * (v[k - 2] + v[k + 2]);
    h[6] = kw2 * v[6] + kw1 * (v[5] + v[7]) + kw0 * (v[4] + ep8);
    h[7] = kw2 * v[7] + kw1 * (v[6] + ep8) + kw0 * (v[5] + ep9);

    float s[8], a[8], p[8];
#pragma unroll
    for (int k = 0; k < 8; ++k) s[k] = h[k] + seqf(lane * 8 + k) + DEF_OFF_F;

    float sm1 = __shfl_up(s[7], 1, 64);
    if (lane == 0) sm1 = 0.0f;
    a[0] = fmaxf((s[0] - sm1) / SCALE_F, 0.0f) * SCALE_F;
#pragma unroll
    for (int k = 1; k < 8; ++k)
      a[k] = fmaxf((s[k] - s[k - 1]) / SCALE_F, 0.0f) * SCALE_F;

    p[0] = a[0];
#pragma unroll
    for (int k = 1; k < 8; ++k) p[k] = p[k - 1] + a[k];
    float incl = p[7];
#pragma unroll
    for (int off = 1; off < 64; off <<= 1) {
      float n = __shfl_up(incl, off, 64);
      if (lane >= off) incl += n;
    }
    float excl = incl - p[7];

    float og[8];
#pragma unroll
    for (int k = 0; k < 8; ++k) {
      float gx = seqf(lane * 8 + k);
      float d = (p[k] + excl) - DEF_OFF_F - gx;
      d = fminf(fmaxf(d, -CLIP_F), CLIP_F);
      og[k] = fminf(fmaxf(d + gx, -1.0f), 1.0f);
    }
    float4* o = (float4*)(gridx + ((size_t)b * WID + i) * WID + lane * 8);
    o[0] = make_float4(og[0], og[1], og[2], og[3]);
    o[1] = make_float4(og[4], og[5], og[6], og[7]);
  } else {
    // ================= y-channel pass 1: 128 rows x 64 cols, 8 segs x 16 =====
    const int bid  = blockIdx.x - 2048;
    const int q    = bid & 3;        // row-quad 0..3 (128 rows each)
    const int tile = (bid >> 2) & 7; // col-tile 0..7 (64 cols each)
    const int b    = bid >> 5;
    const int q0   = q << 7;
    const int gc0  = tile << 6;

    __shared__ float L[KY1_ROWS * KY1_COLS]; // 38.3 KB
    __shared__ float ss[8][64];

    const float* src = pg + ((size_t)b * 2 + 1) * WW;
    for (int idx = threadIdx.x; idx < KY1_ROWS * 18; idx += 512) {
      int lr = idx / 18;
      int k  = idx - lr * 18;
      int gr = refl(q0 - 3 + lr);
      int gcb = gc0 - 4 + (k << 2);
      gcb = gcb < 0 ? 0 : (gcb > WID - 4 ? WID - 4 : gcb);
      float4 v = *(const float4*)(src + (size_t)gr * WID + gcb);
      *(float4*)(&L[lr * KY1_COLS + (k << 2)]) = v;
    }
    __syncthreads();

    const int j   = threadIdx.x & 63;
    const int seg = threadIdx.x >> 6;       // 16-row segment within quad

    int jcc[5];
#pragma unroll
    for (int d = 0; d < 5; ++d)
      jcc[d] = refl(gc0 + j + d - 2) - gc0 + 4; // always in [0,71]

    auto HB = [&](int r) -> float {
      const float* Lr = &L[r * KY1_COLS];
      return kw2 * Lr[jcc[2]] + kw1 * (Lr[jcc[1]] + Lr[jcc[3]])
           + kw0 * (Lr[jcc[0]] + Lr[jcc[4]]);
    };

    const int lri0 = seg * 16 + 2;          // lds row of istart
    float hm2 = HB(lri0 - 2);
    float hm1 = HB(lri0 - 1);
    float hc  = HB(lri0);
    float hp1 = HB(lri0 + 1);
    float hp2 = HB(lri0 + 2);

    const int istart = q0 + seg * 16 - 1;
    float areg[16];
    float sprev = 0.0f, suma = 0.0f;
#pragma unroll
    for (int k = 0; k <= 16; ++k) {
      float blur = kw2 * hc + kw1 * (hm1 + hp1) + kw0 * (hm2 + hp2);
      float s = blur + seqf(istart + k) + DEF_OFF_F;
      if (k == 0) {
        sprev = (q == 0 && seg == 0) ? 0.0f : s;
      } else {
        float a = fmaxf((s - sprev) / SCALE_F, 0.0f) * SCALE_F;
        areg[k - 1] = a;
        suma += a;
        sprev = s;
      }
      if (k < 16) {
        hm2 = hm1; hm1 = hc; hc = hp1; hp1 = hp2;
        hp2 = HB(lri0 + k + 3);
      }
    }

    ss[seg][j] = suma;
    __syncthreads();
    float off = 0.0f;
#pragma unroll
    for (int w = 0; w < 7; ++w)
      if (w < seg) off += ss[w][j];
    if (seg == 7)
      qsum[((size_t)b * 4 + q) * WID + gc0 + j] = off + suma;

    float* ob = gridy + (size_t)b * WW + (size_t)(q0 + seg * 16) * WID + gc0 + j;
    float cum = off;
#pragma unroll
    for (int k = 0; k < 16; ++k) {
      cum += areg[k];
      ob[(size_t)k * WID] = cum;  // partial cumsum; finalized in sample (fused)
    }
  }
}

// ---------------- y-channel pass 2 (fallback only, if qsum must live in out) --
__global__ __launch_bounds__(128)
void ky2_kernel(float* __restrict__ gridy, const float* __restrict__ qsum) {
  const int b = blockIdx.x >> 9;
  const int i = blockIdx.x & 511;
  const int q = i >> 7;
  const int j4 = threadIdx.x << 2;
  const float* qs = qsum + (size_t)b * 4 * WID + j4;
  float ox = 0.f, oy = 0.f, oz = 0.f, ow = 0.f;
  for (int w = 0; w < q; ++w) {
    float4 t = *(const float4*)(qs + (size_t)w * WID);
    ox += t.x; oy += t.y; oz += t.z; ow += t.w;
  }
  const float gy = seqf(i);
  float* p = gridy + ((size_t)b * WID + i) * WID + j4;
  float4 v = *(float4*)p;
  auto fin = [&](float c) -> float {
    float d = c - DEF_OFF_F - gy;
    d = fminf(fmaxf(d, -CLIP_F), CLIP_F);
    return fminf(fmaxf(d + gy, -1.0f), 1.0f);
  };
  v.x = fin(v.x + ox); v.y = fin(v.y + oy);
  v.z = fin(v.z + oz); v.w = fin(v.w + ow);
  *(float4*)p = v;
}

// ---------------- LDS-staged bilinear sample: 1024 thr, 16-row tile ----------
// Displacement <= 7.984 px => rows needed for a 16-row tile: [r0-8, r0+23].
// Linear [32][512] = 64 KB LDS, 2 blocks/CU x 16 waves = 32 waves/CU (100%).
// global_load_lds staging (wave-uniform LDS base + lane*16, per-lane global).
// Gather: lane l reads x ~ l + d (|d|<=8) -> <=2-way bank aliasing (free).
#define STILE  16
#define SROWS  32
#define SAMP_BLOCKS (NB * NC * (WID / STILE))  // 3072

template<bool FUSEY>
__global__ __launch_bounds__(1024, 8)
void sample_kernel(const float* __restrict__ img, const float* __restrict__ gridx,
                   const float* __restrict__ gridy, const float* __restrict__ qsum,
                   float* __restrict__ out) {
  // swizzle: each XCD gets a contiguous chunk so adjacent tiles share halo in L2
  const int nb = (blockIdx.x & 7) * (SAMP_BLOCKS / 8) + (blockIdx.x >> 3);
  const int rt = nb & 31;            // 32 row-tiles
  const int bc = nb >> 5;            // b*3 + c
  const int b  = bc / 3;
  const int c  = bc - b * 3;
  const int r0 = rt * STILE;

  __shared__ float tile[SROWS * WID]; // 64 KB, linear

  const float* ic = img + ((size_t)b * NC + c) * WW;
#pragma unroll
  for (int it = 0; it < 4; ++it) {
    int chunk = it * 1024 + threadIdx.x;  // 0..4095 lane-consecutive 16B chunks
    int lr = chunk >> 7;                  // 128 chunks per 512-float row
    int c4 = (chunk & 127) << 2;
    int gr = r0 - 8 + lr;
    gr = gr < 0 ? 0 : (gr > WID - 1 ? WID - 1 : gr);
    gl_lds16(ic + (size_t)gr * WID + c4, &tile[lr * WID + c4]);
  }
  __syncthreads();

  const int j    = threadIdx.x & 511;
  const int rsub = (threadIdx.x >> 9) << 3;  // 0 or 8

  // cross-quad y-offset: uniform quad per block (128 % STILE == 0)
  float offy = 0.0f;
  if (FUSEY) {
    const int q = r0 >> 7;
    const float* qs = qsum + (size_t)b * 4 * WID + j;
    for (int w = 0; w < q; ++w) offy += qs[(size_t)w * WID];
  }

  float* ob = out + ((size_t)b * NC + c) * WW;
#pragma unroll
  for (int r = 0; r < 8; ++r) {
    const int i = r0 + rsub + r;
    const size_t gidx = ((size_t)b * WID + i) * WID + j;
    float gx = gridx[gidx];
    float gy = gridy[gidx];
    if (FUSEY) {
      const float gyl = seqf(i);
      float d = (gy + offy) - DEF_OFF_F - gyl;
      d = fminf(fmaxf(d, -CLIP_F), CLIP_F);
      gy = fminf(fmaxf(d + gyl, -1.0f), 1.0f);
    }
    float x = (gx + 1.0f) * (0.5f * (float)(WID - 1));
    float y = (gy + 1.0f) * (0.5f * (float)(WID - 1));
    float x0f = floorf(x), y0f = floorf(y);
    int x0 = (int)x0f, y0 = (int)y0f;
    float wx1 = x - x0f, wx0 = 1.0f - wx1;
    float wy1 = y - y0f, wy0 = 1.0f - wy1;
    int x1 = x0 + 1, y1 = y0 + 1;
    int x1c = x1 > WID - 1 ? WID - 1 : x1;
    int y1c = y1 > WID - 1 ? WID - 1 : y1;
    float vx1 = x1 < WID ? 1.0f : 0.0f;
    float vy1 = y1 < WID ? 1.0f : 0.0f;

    float w00 = wx0 * wy0;
    float w01 = wx1 * wy0 * vx1;
    float w10 = wx0 * wy1 * vy1;
    float w11 = wx1 * wy1 * vx1 * vy1;

    int ly0 = y0 - r0 + 8;
    int ly1 = y1c - r0 + 8;
    float v00 = tile[ly0 * WID + x0];
    float v01 = tile[ly0 * WID + x1c];
    float v10 = tile[ly1 * WID + x0];
    float v11 = tile[ly1 * WID + x1c];

    ob[(size_t)i * WID + j] = w00 * v00 + w01 * v01 + w10 * v10 + w11 * v11;
  }
}

extern "C" void kernel_launch(void* const* d_in, const int* in_sizes, int n_in,
                              void* d_out, int out_size, void* d_ws, size_t ws_size,
                              hipStream_t stream) {
  const float* img = (const float*)d_in[0];
  const float* pg  = (const float*)d_in[1];
  float* out = (float*)d_out;

  float* gridx = (float*)d_ws;
  float* gridy = gridx + (size_t)NB * WW;

  const size_t grids_bytes = (size_t)2 * NB * WW * sizeof(float);
  const size_t qsum_bytes  = (size_t)NB * 4 * WID * sizeof(float); // 256 KB
  const bool ws_fits = (ws_size >= grids_bytes + qsum_bytes);
  float* qsum = ws_fits ? (float*)((char*)d_ws + grids_bytes)
                        : (float*)d_out;  // fallback scratch; needs ky2 pass

  double sigma = 5.0 * 0.15 + 0.35;
  double p0 = exp(-0.5 * (2.0 / sigma) * (2.0 / sigma));
  double p1 = exp(-0.5 * (1.0 / sigma) * (1.0 / sigma));
  double p2 = 1.0;
  double sum = 2.0 * p0 + 2.0 * p1 + p2;
  float kw0 = (float)(p0 / sum), kw1 = (float)(p1 / sum), kw2 = (float)(p2 / sum);

  grid_kernel<<<2048 + NB * 32, 512, 0, stream>>>(pg, gridx, gridy, qsum,
                                                  kw0, kw1, kw2);
  if (ws_fits) {
    sample_kernel<true><<<SAMP_BLOCKS, 1024, 0, stream>>>(img, gridx, gridy,
                                                          qsum, out);
  } else {
    ky2_kernel<<<NB * WID, 128, 0, stream>>>(gridy, qsum);
    sample_kernel<false><<<SAMP_BLOCKS, 1024, 0, stream>>>(img, gridx, gridy,
                                                           qsum, out);
  }
}

// Round 5
// 257.516 us; speedup vs baseline: 1.1788x; 1.0135x over previous
//
#include <hip/hip_runtime.h>
#include <math.h>

#define WID 512
#define NB  32
#define NC  3
#define WW  (WID * WID)

constexpr float SCALE_F   = (float)(4.0 / 511.0);
constexpr float DEF_OFF_F = (float)((2.0 + 4.0 / 511.0) * 0.5);
constexpr float CLIP_F    = 0.03125f; // PIX_W*EPS -> max displacement 7.984 px

__device__ __forceinline__ int refl(int r) {
  r = r < 0 ? -r : r;
  return r > WID - 1 ? 2 * (WID - 1) - r : r;
}

__device__ __forceinline__ float seqf(int i) {
  return ((float)(2 * i - 511)) / 511.0f;
}

__device__ __forceinline__ void gl_lds16(const float* g, float* l) {
  __builtin_amdgcn_global_load_lds(
      (const __attribute__((address_space(1))) void*)g,
      (__attribute__((address_space(3))) void*)l, 16, 0, 0);
}

// ---------------- merged grid kernel: kx (blocks 0..2047) + ky1 (2048..3071) --
#define KY1_ROWS 133
#define KY1_COLS 72

__global__ __launch_bounds__(512)
void grid_kernel(const float* __restrict__ pg, float* __restrict__ gridx,
                 float* __restrict__ gridy, float* __restrict__ qsum,
                 float kw0, float kw1, float kw2) {
  if (blockIdx.x < 2048) {
    // ================= x-channel: wave-per-row, no LDS, no barriers ==========
    const int lane = threadIdx.x & 63;
    const int wv   = threadIdx.x >> 6;
    const int R = blockIdx.x * 8 + wv;
    const int b = R >> 9;
    const int i = R & (WID - 1);
    const float* base = pg + (size_t)b * 2 * WW;

    float v[8] = {0.f,0.f,0.f,0.f,0.f,0.f,0.f,0.f};
    const int rows[5] = {refl(i - 2), refl(i - 1), i, refl(i + 1), refl(i + 2)};
    const float wts[5] = {kw0, kw1, kw2, kw1, kw0};
#pragma unroll
    for (int r = 0; r < 5; ++r) {
      const float4* p = (const float4*)(base + (size_t)rows[r] * WID + lane * 8);
      float4 A = p[0], Bq = p[1];
      float w = wts[r];
      v[0] += w * A.x;  v[1] += w * A.y;  v[2] += w * A.z;  v[3] += w * A.w;
      v[4] += w * Bq.x; v[5] += w * Bq.y; v[6] += w * Bq.z; v[7] += w * Bq.w;
    }

    float em1 = __shfl_up(v[7], 1, 64);
    float em2 = __shfl_up(v[6], 1, 64);
    float ep8 = __shfl_down(v[0], 1, 64);
    float ep9 = __shfl_down(v[1], 1, 64);
    if (lane == 0)  { em1 = v[1]; em2 = v[2]; }
    if (lane == 63) { ep8 = v[6]; ep9 = v[5]; }

    float h[8];
    h[0] = kw2 * v[0] + kw1 * (em1 + v[1]) + kw0 * (em2 + v[2]);
    h[1] = kw2 * v[1] + kw1 * (v[0] + v[2]) + kw0 * (em1 + v[3]);
#pragma unroll
    for (int k = 2; k < 6; ++k)
      h[k] = kw2 * v[k] + kw1 * (v[k - 1] + v[k + 1]) + kw0 * (v[k - 2] + v[k + 2]);
    h[6] = kw2 * v[6] + kw1 * (v[5] + v[7]) + kw0 * (v[4] + ep8);
    h[7] = kw2 * v[7] + kw1 * (v[6] + ep8) + kw0 * (v[5] + ep9);

    float s[8], a[8], p[8];
#pragma unroll
    for (int k = 0; k < 8; ++k) s[k] = h[k] + seqf(lane * 8 + k) + DEF_OFF_F;

    float sm1 = __shfl_up(s[7], 1, 64);
    if (lane == 0) sm1 = 0.0f;
    a[0] = fmaxf((s[0] - sm1) / SCALE_F, 0.0f) * SCALE_F;
#pragma unroll
    for (int k = 1; k < 8; ++k)
      a[k] = fmaxf((s[k] - s[k - 1]) / SCALE_F, 0.0f) * SCALE_F;

    p[0] = a[0];
#pragma unroll
    for (int k = 1; k < 8; ++k) p[k] = p[k - 1] + a[k];
    float incl = p[7];
#pragma unroll
    for (int off = 1; off < 64; off <<= 1) {
      float n = __shfl_up(incl, off, 64);
      if (lane >= off) incl += n;
    }
    float excl = incl - p[7];

    float og[8];
#pragma unroll
    for (int k = 0; k < 8; ++k) {
      float gx = seqf(lane * 8 + k);
      float d = (p[k] + excl) - DEF_OFF_F - gx;
      d = fminf(fmaxf(d, -CLIP_F), CLIP_F);
      og[k] = fminf(fmaxf(d + gx, -1.0f), 1.0f);
    }
    float4* o = (float4*)(gridx + ((size_t)b * WID + i) * WID + lane * 8);
    o[0] = make_float4(og[0], og[1], og[2], og[3]);
    o[1] = make_float4(og[4], og[5], og[6], og[7]);
  } else {
    // ================= y-channel pass 1: 128 rows x 64 cols, 8 segs x 16 =====
    const int bid  = blockIdx.x - 2048;
    const int q    = bid & 3;        // row-quad 0..3 (128 rows each)
    const int tile = (bid >> 2) & 7; // col-tile 0..7 (64 cols each)
    const int b    = bid >> 5;
    const int q0   = q << 7;
    const int gc0  = tile << 6;

    __shared__ float L[KY1_ROWS * KY1_COLS]; // 38.3 KB
    __shared__ float ss[8][64];

    // gl_lds staging: LDS offset = idx*16B exactly (72 floats = 18 chunks/row),
    // so dest is linear in lane -> legal for global_load_lds.
    const float* src = pg + ((size_t)b * 2 + 1) * WW;
    {
      float* lbase = &L[0];
      for (int idx = threadIdx.x; idx < KY1_ROWS * 18; idx += 512) {
        int lr = idx / 18;
        int k  = idx - lr * 18;
        int gr = refl(q0 - 3 + lr);
        int gcb = gc0 - 4 + (k << 2);
        gcb = gcb < 0 ? 0 : (gcb > WID - 4 ? WID - 4 : gcb);
        gl_lds16(src + (size_t)gr * WID + gcb, lbase + (idx << 2));
      }
    }
    __syncthreads();

    const int j   = threadIdx.x & 63;
    const int seg = threadIdx.x >> 6;       // 16-row segment within quad

    int jcc[5];
#pragma unroll
    for (int d = 0; d < 5; ++d)
      jcc[d] = refl(gc0 + j + d - 2) - gc0 + 4; // always in [0,71]

    auto HB = [&](int r) -> float {
      const float* Lr = &L[r * KY1_COLS];
      return kw2 * Lr[jcc[2]] + kw1 * (Lr[jcc[1]] + Lr[jcc[3]])
           + kw0 * (Lr[jcc[0]] + Lr[jcc[4]]);
    };

    const int lri0 = seg * 16 + 2;          // lds row of istart
    float hm2 = HB(lri0 - 2);
    float hm1 = HB(lri0 - 1);
    float hc  = HB(lri0);
    float hp1 = HB(lri0 + 1);
    float hp2 = HB(lri0 + 2);

    const int istart = q0 + seg * 16 - 1;
    float areg[16];
    float sprev = 0.0f, suma = 0.0f;
#pragma unroll
    for (int k = 0; k <= 16; ++k) {
      float blur = kw2 * hc + kw1 * (hm1 + hp1) + kw0 * (hm2 + hp2);
      float s = blur + seqf(istart + k) + DEF_OFF_F;
      if (k == 0) {
        sprev = (q == 0 && seg == 0) ? 0.0f : s;
      } else {
        float a = fmaxf((s - sprev) / SCALE_F, 0.0f) * SCALE_F;
        areg[k - 1] = a;
        suma += a;
        sprev = s;
      }
      if (k < 16) {
        hm2 = hm1; hm1 = hc; hc = hp1; hp1 = hp2;
        hp2 = HB(lri0 + k + 3);
      }
    }

    ss[seg][j] = suma;
    __syncthreads();
    float off = 0.0f;
#pragma unroll
    for (int w = 0; w < 7; ++w)
      if (w < seg) off += ss[w][j];
    if (seg == 7)
      qsum[((size_t)b * 4 + q) * WID + gc0 + j] = off + suma;

    float* ob = gridy + (size_t)b * WW + (size_t)(q0 + seg * 16) * WID + gc0 + j;
    float cum = off;
#pragma unroll
    for (int k = 0; k < 16; ++k) {
      cum += areg[k];
      ob[(size_t)k * WID] = cum;  // partial cumsum; finalized in sample (fused)
    }
  }
}

// ---------------- y-channel pass 2 (fallback only, if qsum must live in out) --
__global__ __launch_bounds__(128)
void ky2_kernel(float* __restrict__ gridy, const float* __restrict__ qsum) {
  const int b = blockIdx.x >> 9;
  const int i = blockIdx.x & 511;
  const int q = i >> 7;
  const int j4 = threadIdx.x << 2;
  const float* qs = qsum + (size_t)b * 4 * WID + j4;
  float ox = 0.f, oy = 0.f, oz = 0.f, ow = 0.f;
  for (int w = 0; w < q; ++w) {
    float4 t = *(const float4*)(qs + (size_t)w * WID);
    ox += t.x; oy += t.y; oz += t.z; ow += t.w;
  }
  const float gy = seqf(i);
  float* p = gridy + ((size_t)b * WID + i) * WID + j4;
  float4 v = *(float4*)p;
  auto fin = [&](float c) -> float {
    float d = c - DEF_OFF_F - gy;
    d = fminf(fmaxf(d, -CLIP_F), CLIP_F);
    return fminf(fmaxf(d + gy, -1.0f), 1.0f);
  };
  v.x = fin(v.x + ox); v.y = fin(v.y + oy);
  v.z = fin(v.z + oz); v.w = fin(v.w + ow);
  *(float4*)p = v;
}

// ---------------- LDS-staged bilinear sample: 1024 thr, 16-row tile ----------
// Rows [r0-8, r0+23] staged; linear 64 KB tile, 2 blocks/CU (32 waves, 100%).
// BANK SWIZZLE (both-sides, m173 pattern): row stride 512 floats == bank-
// aligned, so same-x different-row reads collide. Store float fx of LDS row lr
// at fx ^ ((lr&7)<<2); achieved by XOR-ing the SOURCE chunk index (lr&7) while
// keeping the gl_lds dest linear. Reads apply the same XOR keyed on ly.
// ILP: pixels processed in 4-wide batches -- all grid loads issued first, then
// coords, then all 16 LDS reads (static indices only).
#define STILE  16
#define SROWS  32
#define SAMP_BLOCKS (NB * NC * (WID / STILE))  // 3072

template<bool FUSEY>
__global__ __launch_bounds__(1024, 8)
void sample_kernel(const float* __restrict__ img, const float* __restrict__ gridx,
                   const float* __restrict__ gridy, const float* __restrict__ qsum,
                   float* __restrict__ out) {
  // swizzle: each XCD gets a contiguous chunk so adjacent tiles share halo in L2
  const int nb = (blockIdx.x & 7) * (SAMP_BLOCKS / 8) + (blockIdx.x >> 3);
  const int rt = nb & 31;            // 32 row-tiles
  const int bc = nb >> 5;            // b*3 + c
  const int b  = bc / 3;
  const int c  = bc - b * 3;
  const int r0 = rt * STILE;

  __shared__ float tile[SROWS * WID]; // 64 KB, linear dest

  const float* ic = img + ((size_t)b * NC + c) * WW;
#pragma unroll
  for (int it = 0; it < 4; ++it) {
    int chunk = it * 1024 + threadIdx.x;  // 0..4095 16B chunks, lane-linear dest
    int lr = chunk >> 7;                  // 128 chunks per 512-float row
    int cx = chunk & 127;
    int sc = cx ^ (lr & 7);               // pre-swizzled SOURCE chunk
    int gr = r0 - 8 + lr;
    gr = gr < 0 ? 0 : (gr > WID - 1 ? WID - 1 : gr);
    gl_lds16(ic + (size_t)gr * WID + (sc << 2), &tile[chunk << 2]);
  }
  __syncthreads();

  const int j    = threadIdx.x & 511;
  const int rsub = (threadIdx.x >> 9) << 3;  // 0 or 8

  // cross-quad y-offset: uniform quad per block (128 % STILE == 0)
  float offy = 0.0f;
  if (FUSEY) {
    const int q = r0 >> 7;
    const float* qs = qsum + (size_t)b * 4 * WID + j;
    for (int w = 0; w < q; ++w) offy += qs[(size_t)w * WID];
  }

  float* ob = out + ((size_t)b * NC + c) * WW;
  const float* gxp = gridx + ((size_t)b * WID + r0 + rsub) * WID + j;
  const float* gyp = gridy + ((size_t)b * WID + r0 + rsub) * WID + j;

#pragma unroll
  for (int half = 0; half < 2; ++half) {
    const int ib = rsub + half * 4;       // tile-row base of this batch
    // ---- phase A: issue all 8 grid loads ----
    float gxv[4], gyv[4];
#pragma unroll
    for (int r = 0; r < 4; ++r) {
      gxv[r] = gxp[(size_t)(half * 4 + r) * WID];
      gyv[r] = gyp[(size_t)(half * 4 + r) * WID];
    }
    // ---- phase B: coords + weights ----
    float wx0v[4], wx1v[4], wy0v[4], wy1v[4];
    int i00[4], i01[4], i10[4], i11[4];
#pragma unroll
    for (int r = 0; r < 4; ++r) {
      const int i = r0 + ib + r;
      float gx = gxv[r];
      float gy = gyv[r];
      if (FUSEY) {
        const float gyl = seqf(i);
        float d = (gy + offy) - DEF_OFF_F - gyl;
        d = fminf(fmaxf(d, -CLIP_F), CLIP_F);
        gy = fminf(fmaxf(d + gyl, -1.0f), 1.0f);
      }
      float x = (gx + 1.0f) * (0.5f * (float)(WID - 1));
      float y = (gy + 1.0f) * (0.5f * (float)(WID - 1));
      float x0f = floorf(x), y0f = floorf(y);
      int x0 = (int)x0f, y0 = (int)y0f;
      wx1v[r] = x - x0f; wx0v[r] = 1.0f - wx1v[r];
      wy1v[r] = y - y0f; wy0v[r] = 1.0f - wy1v[r];
      // clamp-trick: +1 taps that fall OOB have weight exactly 0
      int dx = x0 < WID - 1 ? 1 : 0;
      int dy = y0 < WID - 1 ? 1 : 0;
      int ly0 = y0 - r0 + 8;
      int ly1 = ly0 + dy;
      int k0 = (ly0 & 7) << 2;
      int k1 = (ly1 & 7) << 2;
      i00[r] = (ly0 << 9) + (x0 ^ k0);
      i01[r] = (ly0 << 9) + ((x0 + dx) ^ k0);
      i10[r] = (ly1 << 9) + (x0 ^ k1);
      i11[r] = (ly1 << 9) + ((x0 + dx) ^ k1);
    }
    // ---- phase C: all 16 LDS reads ----
    float v00[4], v01[4], v10[4], v11[4];
#pragma unroll
    for (int r = 0; r < 4; ++r) {
      v00[r] = tile[i00[r]];
      v01[r] = tile[i01[r]];
      v10[r] = tile[i10[r]];
      v11[r] = tile[i11[r]];
    }
    // ---- phase D: fma + store ----
#pragma unroll
    for (int r = 0; r < 4; ++r) {
      const int i = r0 + ib + r;
      ob[(size_t)i * WID + j] =
          wy0v[r] * (wx0v[r] * v00[r] + wx1v[r] * v01[r]) +
          wy1v[r] * (wx0v[r] * v10[r] + wx1v[r] * v11[r]);
    }
  }
}

extern "C" void kernel_launch(void* const* d_in, const int* in_sizes, int n_in,
                              void* d_out, int out_size, void* d_ws, size_t ws_size,
                              hipStream_t stream) {
  const float* img = (const float*)d_in[0];
  const float* pg  = (const float*)d_in[1];
  float* out = (float*)d_out;

  float* gridx = (float*)d_ws;
  float* gridy = gridx + (size_t)NB * WW;

  const size_t grids_bytes = (size_t)2 * NB * WW * sizeof(float);
  const size_t qsum_bytes  = (size_t)NB * 4 * WID * sizeof(float); // 256 KB
  const bool ws_fits = (ws_size >= grids_bytes + qsum_bytes);
  float* qsum = ws_fits ? (float*)((char*)d_ws + grids_bytes)
                        : (float*)d_out;  // fallback scratch; needs ky2 pass

  double sigma = 5.0 * 0.15 + 0.35;
  double p0 = exp(-0.5 * (2.0 / sigma) * (2.0 / sigma));
  double p1 = exp(-0.5 * (1.0 / sigma) * (1.0 / sigma));
  double p2 = 1.0;
  double sum = 2.0 * p0 + 2.0 * p1 + p2;
  float kw0 = (float)(p0 / sum), kw1 = (float)(p1 / sum), kw2 = (float)(p2 / sum);

  grid_kernel<<<2048 + NB * 32, 512, 0, stream>>>(pg, gridx, gridy, qsum,
                                                  kw0, kw1, kw2);
  if (ws_fits) {
    sample_kernel<true><<<SAMP_BLOCKS, 1024, 0, stream>>>(img, gridx, gridy,
                                                          qsum, out);
  } else {
    ky2_kernel<<<NB * WID, 128, 0, stream>>>(gridy, qsum);
    sample_kernel<false><<<SAMP_BLOCKS, 1024, 0, stream>>>(img, gridx, gridy,
                                                           qsum, out);
  }
}

// Round 6
// 254.001 us; speedup vs baseline: 1.1951x; 1.0138x over previous
//
#include <hip/hip_runtime.h>
#include <math.h>

#define WID 512
#define NB  32
#define NC  3
#define WW  (WID * WID)

constexpr float SCALE_F   = (float)(4.0 / 511.0);
constexpr float DEF_OFF_F = (float)((2.0 + 4.0 / 511.0) * 0.5);
constexpr float CLIP_F    = 0.03125f; // PIX_W*EPS -> max displacement 7.984 px

__device__ __forceinline__ int refl(int r) {
  r = r < 0 ? -r : r;
  return r > WID - 1 ? 2 * (WID - 1) - r : r;
}

// (2i-511)/511 as a single fma -- NO f32 divide (harness has no -ffast-math;
// /511.0f emits the full div_scale/rcp/fixup sequence, ~10 instrs).
// <=1 ulp vs the divide; bilinear+clamp are continuous so this is safe.
__device__ __forceinline__ float seqf(int i) {
  return fmaf((float)i, 2.0f / 511.0f, -1.0f);
}

__device__ __forceinline__ void gl_lds16(const float* g, float* l) {
  __builtin_amdgcn_global_load_lds(
      (const __attribute__((address_space(1))) void*)g,
      (__attribute__((address_space(3))) void*)l, 16, 0, 0);
}

// ---------------- merged grid kernel: kx (blocks 0..2047) + ky1 (2048..3071) --
#define KY1_ROWS 133
#define KY1_COLS 72

__global__ __launch_bounds__(512)
void grid_kernel(const float* __restrict__ pg, float* __restrict__ gridx,
                 float* __restrict__ gridy, float* __restrict__ qsum,
                 float kw0, float kw1, float kw2) {
  if (blockIdx.x < 2048) {
    // ================= x-channel: wave-per-row, no LDS, no barriers ==========
    const int lane = threadIdx.x & 63;
    const int wv   = threadIdx.x >> 6;
    const int R = blockIdx.x * 8 + wv;
    const int b = R >> 9;
    const int i = R & (WID - 1);
    const float* base = pg + (size_t)b * 2 * WW;

    float v[8] = {0.f,0.f,0.f,0.f,0.f,0.f,0.f,0.f};
    const int rows[5] = {refl(i - 2), refl(i - 1), i, refl(i + 1), refl(i + 2)};
    const float wts[5] = {kw0, kw1, kw2, kw1, kw0};
#pragma unroll
    for (int r = 0; r < 5; ++r) {
      const float4* p = (const float4*)(base + (size_t)rows[r] * WID + lane * 8);
      float4 A = p[0], Bq = p[1];
      float w = wts[r];
      v[0] += w * A.x;  v[1] += w * A.y;  v[2] += w * A.z;  v[3] += w * A.w;
      v[4] += w * Bq.x; v[5] += w * Bq.y; v[6] += w * Bq.z; v[7] += w * Bq.w;
    }

    float em1 = __shfl_up(v[7], 1, 64);
    float em2 = __shfl_up(v[6], 1, 64);
    float ep8 = __shfl_down(v[0], 1, 64);
    float ep9 = __shfl_down(v[1], 1, 64);
    if (lane == 0)  { em1 = v[1]; em2 = v[2]; }
    if (lane == 63) { ep8 = v[6]; ep9 = v[5]; }

    float h[8];
    h[0] = kw2 * v[0] + kw1 * (em1 + v[1]) + kw0 * (em2 + v[2]);
    h[1] = kw2 * v[1] + kw1 * (v[0] + v[2]) + kw0 * (em1 + v[3]);
#pragma unroll
    for (int k = 2; k < 6; ++k)
      h[k] = kw2 * v[k] + kw1 * (v[k - 1] + v[k + 1]) + kw0 * (v[k - 2] + v[k + 2]);
    h[6] = kw2 * v[6] + kw1 * (v[5] + v[7]) + kw0 * (v[4] + ep8);
    h[7] = kw2 * v[7] + kw1 * (v[6] + ep8) + kw0 * (v[5] + ep9);

    float s[8], a[8], p[8];
#pragma unroll
    for (int k = 0; k < 8; ++k) s[k] = h[k] + seqf(lane * 8 + k) + DEF_OFF_F;

    float sm1 = __shfl_up(s[7], 1, 64);
    if (lane == 0) sm1 = 0.0f;
    // max((s-sprev)/SCALE,0)*SCALE == max(s-sprev,0): SCALE>0, and the
    // div+mul round-trip only adds rounding noise (and a real divide).
    a[0] = fmaxf(s[0] - sm1, 0.0f);
#pragma unroll
    for (int k = 1; k < 8; ++k)
      a[k] = fmaxf(s[k] - s[k - 1], 0.0f);

    p[0] = a[0];
#pragma unroll
    for (int k = 1; k < 8; ++k) p[k] = p[k - 1] + a[k];
    float incl = p[7];
#pragma unroll
    for (int off = 1; off < 64; off <<= 1) {
      float n = __shfl_up(incl, off, 64);
      if (lane >= off) incl += n;
    }
    float excl = incl - p[7];

    float og[8];
#pragma unroll
    for (int k = 0; k < 8; ++k) {
      float gx = seqf(lane * 8 + k);
      float d = (p[k] + excl) - DEF_OFF_F - gx;
      d = fminf(fmaxf(d, -CLIP_F), CLIP_F);
      og[k] = fminf(fmaxf(d + gx, -1.0f), 1.0f);
    }
    float4* o = (float4*)(gridx + ((size_t)b * WID + i) * WID + lane * 8);
    o[0] = make_float4(og[0], og[1], og[2], og[3]);
    o[1] = make_float4(og[4], og[5], og[6], og[7]);
  } else {
    // ================= y-channel pass 1: 128 rows x 64 cols, 8 segs x 16 =====
    const int bid  = blockIdx.x - 2048;
    const int q    = bid & 3;        // row-quad 0..3 (128 rows each)
    const int tile = (bid >> 2) & 7; // col-tile 0..7 (64 cols each)
    const int b    = bid >> 5;
    const int q0   = q << 7;
    const int gc0  = tile << 6;

    __shared__ float L[KY1_ROWS * KY1_COLS]; // 38.3 KB
    __shared__ float ss[8][64];

    // gl_lds staging: LDS offset = idx*16B exactly (72 floats = 18 chunks/row),
    // so dest is linear in lane -> legal for global_load_lds.
    const float* src = pg + ((size_t)b * 2 + 1) * WW;
    {
      float* lbase = &L[0];
      for (int idx = threadIdx.x; idx < KY1_ROWS * 18; idx += 512) {
        int lr = idx / 18;
        int k  = idx - lr * 18;
        int gr = refl(q0 - 3 + lr);
        int gcb = gc0 - 4 + (k << 2);
        gcb = gcb < 0 ? 0 : (gcb > WID - 4 ? WID - 4 : gcb);
        gl_lds16(src + (size_t)gr * WID + gcb, lbase + (idx << 2));
      }
    }
    __syncthreads();

    const int j   = threadIdx.x & 63;
    const int seg = threadIdx.x >> 6;       // 16-row segment within quad

    int jcc[5];
#pragma unroll
    for (int d = 0; d < 5; ++d)
      jcc[d] = refl(gc0 + j + d - 2) - gc0 + 4; // always in [0,71]

    auto HB = [&](int r) -> float {
      const float* Lr = &L[r * KY1_COLS];
      return kw2 * Lr[jcc[2]] + kw1 * (Lr[jcc[1]] + Lr[jcc[3]])
           + kw0 * (Lr[jcc[0]] + Lr[jcc[4]]);
    };

    const int lri0 = seg * 16 + 2;          // lds row of istart
    float hm2 = HB(lri0 - 2);
    float hm1 = HB(lri0 - 1);
    float hc  = HB(lri0);
    float hp1 = HB(lri0 + 1);
    float hp2 = HB(lri0 + 2);

    const int istart = q0 + seg * 16 - 1;
    float areg[16];
    float sprev = 0.0f, suma = 0.0f;
#pragma unroll
    for (int k = 0; k <= 16; ++k) {
      float blur = kw2 * hc + kw1 * (hm1 + hp1) + kw0 * (hm2 + hp2);
      float s = blur + seqf(istart + k) + DEF_OFF_F;
      if (k == 0) {
        sprev = (q == 0 && seg == 0) ? 0.0f : s;
      } else {
        float a = fmaxf(s - sprev, 0.0f);   // div/mul round-trip removed
        areg[k - 1] = a;
        suma += a;
        sprev = s;
      }
      if (k < 16) {
        hm2 = hm1; hm1 = hc; hc = hp1; hp1 = hp2;
        hp2 = HB(lri0 + k + 3);
      }
    }

    ss[seg][j] = suma;
    __syncthreads();
    float off = 0.0f;
#pragma unroll
    for (int w = 0; w < 7; ++w)
      if (w < seg) off += ss[w][j];
    if (seg == 7)
      qsum[((size_t)b * 4 + q) * WID + gc0 + j] = off + suma;

    float* ob = gridy + (size_t)b * WW + (size_t)(q0 + seg * 16) * WID + gc0 + j;
    float cum = off;
#pragma unroll
    for (int k = 0; k < 16; ++k) {
      cum += areg[k];
      ob[(size_t)k * WID] = cum;  // partial cumsum; finalized in sample (fused)
    }
  }
}

// ---------------- y-channel pass 2 (fallback only, if qsum must live in out) --
__global__ __launch_bounds__(128)
void ky2_kernel(float* __restrict__ gridy, const float* __restrict__ qsum) {
  const int b = blockIdx.x >> 9;
  const int i = blockIdx.x & 511;
  const int q = i >> 7;
  const int j4 = threadIdx.x << 2;
  const float* qs = qsum + (size_t)b * 4 * WID + j4;
  float ox = 0.f, oy = 0.f, oz = 0.f, ow = 0.f;
  for (int w = 0; w < q; ++w) {
    float4 t = *(const float4*)(qs + (size_t)w * WID);
    ox += t.x; oy += t.y; oz += t.z; ow += t.w;
  }
  const float gy = seqf(i);
  float* p = gridy + ((size_t)b * WID + i) * WID + j4;
  float4 v = *(float4*)p;
  auto fin = [&](float c) -> float {
    float d = c - DEF_OFF_F - gy;
    d = fminf(fmaxf(d, -CLIP_F), CLIP_F);
    return fminf(fmaxf(d + gy, -1.0f), 1.0f);
  };
  v.x = fin(v.x + ox); v.y = fin(v.y + oy);
  v.z = fin(v.z + oz); v.w = fin(v.w + ow);
  *(float4*)p = v;
}

// ---------------- LDS-staged bilinear sample: 1024 thr, 16-row tile ----------
// Rows [r0-8, r0+23] staged; linear 64 KB tile, 2 blocks/CU (32 waves, 100%).
// No LDS swizzle: gather conflicts cost ~5 us on the (non-critical) LDS pipe,
// while the swizzle index math cost ~8 us on the (critical) VALU pipe (r5).
// Grid loads + qsum prefetched into VGPRs BEFORE the barrier so their HBM
// latency hides under the staging drain (T14).
#define STILE  16
#define SROWS  32
#define SAMP_BLOCKS (NB * NC * (WID / STILE))  // 3072

template<bool FUSEY>
__global__ __launch_bounds__(1024, 8)
void sample_kernel(const float* __restrict__ img, const float* __restrict__ gridx,
                   const float* __restrict__ gridy, const float* __restrict__ qsum,
                   float* __restrict__ out) {
  // swizzle: each XCD gets a contiguous chunk so adjacent tiles share halo in L2
  const int nb = (blockIdx.x & 7) * (SAMP_BLOCKS / 8) + (blockIdx.x >> 3);
  const int rt = nb & 31;            // 32 row-tiles
  const int bc = nb >> 5;            // b*3 + c
  const int b  = bc / 3;
  const int c  = bc - b * 3;
  const int r0 = rt * STILE;

  __shared__ float tile[SROWS * WID]; // 64 KB, linear

  const float* ic = img + ((size_t)b * NC + c) * WW;
#pragma unroll
  for (int it = 0; it < 4; ++it) {
    int chunk = it * 1024 + threadIdx.x;  // 0..4095 lane-consecutive 16B chunks
    int lr = chunk >> 7;                  // 128 chunks per 512-float row
    int c4 = (chunk & 127) << 2;
    int gr = r0 - 8 + lr;
    gr = gr < 0 ? 0 : (gr > WID - 1 ? WID - 1 : gr);
    gl_lds16(ic + (size_t)gr * WID + c4, &tile[chunk << 2]);
  }

  const int j     = threadIdx.x & 511;
  const int rsub  = (threadIdx.x >> 9) << 3;  // 0 or 8
  const int ibase = r0 + rsub;

  // ---- prefetch (overlaps with staging, completes at the same barrier) ----
  const float* gxp = gridx + ((size_t)b * WID + ibase) * WID + j;
  const float* gyp = gridy + ((size_t)b * WID + ibase) * WID + j;
  float gxv[8], gyv[8];
#pragma unroll
  for (int r = 0; r < 8; ++r) {
    gxv[r] = gxp[(size_t)r * WID];
    gyv[r] = gyp[(size_t)r * WID];
  }
  float offc = -DEF_OFF_F;   // hoisted: (gy + offy) - DEF_OFF == gy + offc
  if (FUSEY) {
    const int q = r0 >> 7;   // cross-quad offset, uniform per block
    const float* qs = qsum + (size_t)b * 4 * WID + j;
    for (int w = 0; w < q; ++w) offc += qs[(size_t)w * WID];
  }

  __syncthreads();

  float* ob = out + ((size_t)b * NC + c) * WW;
#pragma unroll
  for (int r = 0; r < 8; ++r) {
    const int i = ibase + r;
    float gx = gxv[r];
    float gy = gyv[r];
    if (FUSEY) {
      const float gyl = seqf(i);               // 1 cvt + 1 fma, no divide
      float d = (gy + offc) - gyl;
      d = fminf(fmaxf(d, -CLIP_F), CLIP_F);
      gy = fminf(fmaxf(d + gyl, -1.0f), 1.0f);
    }
    float x = (gx + 1.0f) * (0.5f * (float)(WID - 1));
    float y = (gy + 1.0f) * (0.5f * (float)(WID - 1));
    float x0f = floorf(x), y0f = floorf(y);
    int x0 = (int)x0f, y0 = (int)y0f;
    float wx1 = x - x0f;
    float wy1 = y - y0f;
    // +1 taps that would fall OOB have bilinear weight exactly 0
    int dx = x0 < WID - 1 ? 1 : 0;
    int dy = y0 < WID - 1 ? WID : 0;          // row step in floats
    int i00 = ((y0 - r0 + 8) << 9) + x0;      // ly in [0,31] by construction

    float v00 = tile[i00];
    float v01 = tile[i00 + dx];
    float v10 = tile[i00 + dy];
    float v11 = tile[i00 + dy + dx];

    float top = v00 + wx1 * (v01 - v00);      // lerp form: no wx0/wy0 needed
    float bot = v10 + wx1 * (v11 - v10);
    ob[(size_t)i * WID + j] = top + wy1 * (bot - top);
  }
}

extern "C" void kernel_launch(void* const* d_in, const int* in_sizes, int n_in,
                              void* d_out, int out_size, void* d_ws, size_t ws_size,
                              hipStream_t stream) {
  const float* img = (const float*)d_in[0];
  const float* pg  = (const float*)d_in[1];
  float* out = (float*)d_out;

  float* gridx = (float*)d_ws;
  float* gridy = gridx + (size_t)NB * WW;

  const size_t grids_bytes = (size_t)2 * NB * WW * sizeof(float);
  const size_t qsum_bytes  = (size_t)NB * 4 * WID * sizeof(float); // 256 KB
  const bool ws_fits = (ws_size >= grids_bytes + qsum_bytes);
  float* qsum = ws_fits ? (float*)((char*)d_ws + grids_bytes)
                        : (float*)d_out;  // fallback scratch; needs ky2 pass

  double sigma = 5.0 * 0.15 + 0.35;
  double p0 = exp(-0.5 * (2.0 / sigma) * (2.0 / sigma));
  double p1 = exp(-0.5 * (1.0 / sigma) * (1.0 / sigma));
  double p2 = 1.0;
  double sum = 2.0 * p0 + 2.0 * p1 + p2;
  float kw0 = (float)(p0 / sum), kw1 = (float)(p1 / sum), kw2 = (float)(p2 / sum);

  grid_kernel<<<2048 + NB * 32, 512, 0, stream>>>(pg, gridx, gridy, qsum,
                                                  kw0, kw1, kw2);
  if (ws_fits) {
    sample_kernel<true><<<SAMP_BLOCKS, 1024, 0, stream>>>(img, gridx, gridy,
                                                          qsum, out);
  } else {
    ky2_kernel<<<NB * WID, 128, 0, stream>>>(gridy, qsum);
    sample_kernel<false><<<SAMP_BLOCKS, 1024, 0, stream>>>(img, gridx, gridy,
                                                           qsum, out);
  }
}

// Round 7
// 252.535 us; speedup vs baseline: 1.2020x; 1.0058x over previous
//
#include <hip/hip_runtime.h>
#include <math.h>

#define WID 512
#define NB  32
#define NC  3
#define WW  (WID * WID)

constexpr float SCALE_F   = (float)(4.0 / 511.0);
constexpr float DEF_OFF_F = (float)((2.0 + 4.0 / 511.0) * 0.5);
constexpr float CLIP_F    = 0.03125f; // PIX_W*EPS -> max displacement 7.984 px

__device__ __forceinline__ int refl(int r) {
  r = r < 0 ? -r : r;
  return r > WID - 1 ? 2 * (WID - 1) - r : r;
}

// (2i-511)/511 as a single fma -- NO f32 divide (harness has no -ffast-math;
// /511.0f emits the full div_scale/rcp/fixup sequence, ~10 instrs).
// <=1 ulp vs the divide; bilinear+clamp are continuous so this is safe.
__device__ __forceinline__ float seqf(int i) {
  return fmaf((float)i, 2.0f / 511.0f, -1.0f);
}

__device__ __forceinline__ void gl_lds16(const float* g, float* l) {
  __builtin_amdgcn_global_load_lds(
      (const __attribute__((address_space(1))) void*)g,
      (__attribute__((address_space(3))) void*)l, 16, 0, 0);
}

// ---------------- merged grid kernel: kx (blocks 0..2047) + ky1 (2048..3071) --
#define KY1_ROWS 133
#define KY1_COLS 72

__global__ __launch_bounds__(512)
void grid_kernel(const float* __restrict__ pg, float* __restrict__ gridx,
                 float* __restrict__ gridy, float* __restrict__ qsum,
                 float kw0, float kw1, float kw2) {
  if (blockIdx.x < 2048) {
    // ================= x-channel: wave-per-row, no LDS, no barriers ==========
    const int lane = threadIdx.x & 63;
    const int wv   = threadIdx.x >> 6;
    const int R = blockIdx.x * 8 + wv;
    const int b = R >> 9;
    const int i = R & (WID - 1);
    const float* base = pg + (size_t)b * 2 * WW;

    float v[8] = {0.f,0.f,0.f,0.f,0.f,0.f,0.f,0.f};
    const int rows[5] = {refl(i - 2), refl(i - 1), i, refl(i + 1), refl(i + 2)};
    const float wts[5] = {kw0, kw1, kw2, kw1, kw0};
#pragma unroll
    for (int r = 0; r < 5; ++r) {
      const float4* p = (const float4*)(base + (size_t)rows[r] * WID + lane * 8);
      float4 A = p[0], Bq = p[1];
      float w = wts[r];
      v[0] += w * A.x;  v[1] += w * A.y;  v[2] += w * A.z;  v[3] += w * A.w;
      v[4] += w * Bq.x; v[5] += w * Bq.y; v[6] += w * Bq.z; v[7] += w * Bq.w;
    }

    float em1 = __shfl_up(v[7], 1, 64);
    float em2 = __shfl_up(v[6], 1, 64);
    float ep8 = __shfl_down(v[0], 1, 64);
    float ep9 = __shfl_down(v[1], 1, 64);
    if (lane == 0)  { em1 = v[1]; em2 = v[2]; }
    if (lane == 63) { ep8 = v[6]; ep9 = v[5]; }

    float h[8];
    h[0] = kw2 * v[0] + kw1 * (em1 + v[1]) + kw0 * (em2 + v[2]);
    h[1] = kw2 * v[1] + kw1 * (v[0] + v[2]) + kw0 * (em1 + v[3]);
#pragma unroll
    for (int k = 2; k < 6; ++k)
      h[k] = kw2 * v[k] + kw1 * (v[k - 1] + v[k + 1]) + kw0 * (v[k - 2] + v[k + 2]);
    h[6] = kw2 * v[6] + kw1 * (v[5] + v[7]) + kw0 * (v[4] + ep8);
    h[7] = kw2 * v[7] + kw1 * (v[6] + ep8) + kw0 * (v[5] + ep9);

    float s[8], a[8], p[8];
#pragma unroll
    for (int k = 0; k < 8; ++k) s[k] = h[k] + seqf(lane * 8 + k) + DEF_OFF_F;

    float sm1 = __shfl_up(s[7], 1, 64);
    if (lane == 0) sm1 = 0.0f;
    // max((s-sprev)/SCALE,0)*SCALE == max(s-sprev,0): SCALE>0.
    a[0] = fmaxf(s[0] - sm1, 0.0f);
#pragma unroll
    for (int k = 1; k < 8; ++k)
      a[k] = fmaxf(s[k] - s[k - 1], 0.0f);

    p[0] = a[0];
#pragma unroll
    for (int k = 1; k < 8; ++k) p[k] = p[k - 1] + a[k];
    float incl = p[7];
#pragma unroll
    for (int off = 1; off < 64; off <<= 1) {
      float n = __shfl_up(incl, off, 64);
      if (lane >= off) incl += n;
    }
    float excl = incl - p[7];

    float og[8];
#pragma unroll
    for (int k = 0; k < 8; ++k) {
      float gx = seqf(lane * 8 + k);
      float d = (p[k] + excl) - DEF_OFF_F - gx;
      d = fminf(fmaxf(d, -CLIP_F), CLIP_F);
      og[k] = fminf(fmaxf(d + gx, -1.0f), 1.0f);
    }
    float4* o = (float4*)(gridx + ((size_t)b * WID + i) * WID + lane * 8);
    o[0] = make_float4(og[0], og[1], og[2], og[3]);
    o[1] = make_float4(og[4], og[5], og[6], og[7]);
  } else {
    // ================= y-channel pass 1: 128 rows x 64 cols, 8 segs x 16 =====
    const int bid  = blockIdx.x - 2048;
    const int q    = bid & 3;        // row-quad 0..3 (128 rows each)
    const int tile = (bid >> 2) & 7; // col-tile 0..7 (64 cols each)
    const int b    = bid >> 5;
    const int q0   = q << 7;
    const int gc0  = tile << 6;

    __shared__ float L[KY1_ROWS * KY1_COLS]; // 38.3 KB
    __shared__ float ss[8][64];

    // gl_lds staging: LDS offset = idx*16B exactly (72 floats = 18 chunks/row),
    // so dest is linear in lane -> legal for global_load_lds.
    const float* src = pg + ((size_t)b * 2 + 1) * WW;
    {
      float* lbase = &L[0];
      for (int idx = threadIdx.x; idx < KY1_ROWS * 18; idx += 512) {
        int lr = idx / 18;
        int k  = idx - lr * 18;
        int gr = refl(q0 - 3 + lr);
        int gcb = gc0 - 4 + (k << 2);
        gcb = gcb < 0 ? 0 : (gcb > WID - 4 ? WID - 4 : gcb);
        gl_lds16(src + (size_t)gr * WID + gcb, lbase + (idx << 2));
      }
    }
    __syncthreads();

    const int j   = threadIdx.x & 63;
    const int seg = threadIdx.x >> 6;       // 16-row segment within quad

    int jcc[5];
#pragma unroll
    for (int d = 0; d < 5; ++d)
      jcc[d] = refl(gc0 + j + d - 2) - gc0 + 4; // always in [0,71]

    auto HB = [&](int r) -> float {
      const float* Lr = &L[r * KY1_COLS];
      return kw2 * Lr[jcc[2]] + kw1 * (Lr[jcc[1]] + Lr[jcc[3]])
           + kw0 * (Lr[jcc[0]] + Lr[jcc[4]]);
    };

    const int lri0 = seg * 16 + 2;          // lds row of istart
    float hm2 = HB(lri0 - 2);
    float hm1 = HB(lri0 - 1);
    float hc  = HB(lri0);
    float hp1 = HB(lri0 + 1);
    float hp2 = HB(lri0 + 2);

    const int istart = q0 + seg * 16 - 1;
    float areg[16];
    float sprev = 0.0f, suma = 0.0f;
#pragma unroll
    for (int k = 0; k <= 16; ++k) {
      float blur = kw2 * hc + kw1 * (hm1 + hp1) + kw0 * (hm2 + hp2);
      float s = blur + seqf(istart + k) + DEF_OFF_F;
      if (k == 0) {
        sprev = (q == 0 && seg == 0) ? 0.0f : s;
      } else {
        float a = fmaxf(s - sprev, 0.0f);   // div/mul round-trip removed
        areg[k - 1] = a;
        suma += a;
        sprev = s;
      }
      if (k < 16) {
        hm2 = hm1; hm1 = hc; hc = hp1; hp1 = hp2;
        hp2 = HB(lri0 + k + 3);
      }
    }

    ss[seg][j] = suma;
    __syncthreads();
    float off = 0.0f;
#pragma unroll
    for (int w = 0; w < 7; ++w)
      if (w < seg) off += ss[w][j];
    if (seg == 7)
      qsum[((size_t)b * 4 + q) * WID + gc0 + j] = off + suma;

    float* ob = gridy + (size_t)b * WW + (size_t)(q0 + seg * 16) * WID + gc0 + j;
    float cum = off;
#pragma unroll
    for (int k = 0; k < 16; ++k) {
      cum += areg[k];
      ob[(size_t)k * WID] = cum;  // partial cumsum; finalized in sample (fused)
    }
  }
}

// ---------------- y-channel pass 2 (fallback only, if qsum must live in out) --
__global__ __launch_bounds__(128)
void ky2_kernel(float* __restrict__ gridy, const float* __restrict__ qsum) {
  const int b = blockIdx.x >> 9;
  const int i = blockIdx.x & 511;
  const int q = i >> 7;
  const int j4 = threadIdx.x << 2;
  const float* qs = qsum + (size_t)b * 4 * WID + j4;
  float ox = 0.f, oy = 0.f, oz = 0.f, ow = 0.f;
  for (int w = 0; w < q; ++w) {
    float4 t = *(const float4*)(qs + (size_t)w * WID);
    ox += t.x; oy += t.y; oz += t.z; ow += t.w;
  }
  const float gy = seqf(i);
  float* p = gridy + ((size_t)b * WID + i) * WID + j4;
  float4 v = *(float4*)p;
  auto fin = [&](float c) -> float {
    float d = c - DEF_OFF_F - gy;
    d = fminf(fmaxf(d, -CLIP_F), CLIP_F);
    return fminf(fmaxf(d + gy, -1.0f), 1.0f);
  };
  v.x = fin(v.x + ox); v.y = fin(v.y + oy);
  v.z = fin(v.z + oz); v.w = fin(v.w + ow);
  *(float4*)p = v;
}

// ------------- LDS-staged bilinear sample: split-tile 2-phase pipeline -------
// 16-row tile, rows [r0-8, r0+23] staged in TWO phases so the barrier drain
// halves and phase-2 staging (LDS rows 24..31) + B-half grid loads overlap
// with half-A compute (which only touches LDS rows 0..23 -- disjoint).
// Each thread owns col j and 4+4 rows: A = r0+rsel+{0..3}, B = A+8, so both
// halves use all 1024 threads.  Per-half ly ranges: A in [0,23], B in [8,31].
#define STILE  16
#define SROWS  32
#define SAMP_BLOCKS (NB * NC * (WID / STILE))  // 3072

template<bool FUSEY>
__global__ __launch_bounds__(1024, 8)
void sample_kernel(const float* __restrict__ img, const float* __restrict__ gridx,
                   const float* __restrict__ gridy, const float* __restrict__ qsum,
                   float* __restrict__ out) {
  // swizzle: each XCD gets a contiguous chunk so adjacent tiles share halo in L2
  const int nb = (blockIdx.x & 7) * (SAMP_BLOCKS / 8) + (blockIdx.x >> 3);
  const int rt = nb & 31;            // 32 row-tiles
  const int bc = nb >> 5;            // b*3 + c
  const int b  = bc / 3;
  const int c  = bc - b * 3;
  const int r0 = rt * STILE;

  __shared__ float tile[SROWS * WID]; // 64 KB, linear

  const float* ic = img + ((size_t)b * NC + c) * WW;
  // ---- phase-1 stage: LDS rows 0..23 (global r0-8 .. r0+15), 48 KB ----
#pragma unroll
  for (int it = 0; it < 3; ++it) {
    int chunk = it * 1024 + threadIdx.x;  // 0..3071, lane-linear dest
    int lr = chunk >> 7;                  // 128 chunks per 512-float row
    int c4 = (chunk & 127) << 2;
    int gr = r0 - 8 + lr;
    gr = gr < 0 ? 0 : (gr > WID - 1 ? WID - 1 : gr);
    gl_lds16(ic + (size_t)gr * WID + c4, &tile[chunk << 2]);
  }

  const int j    = threadIdx.x & 511;
  const int rsel = (threadIdx.x >> 9) << 2;   // 0 or 4
  const int iA   = r0 + rsel;                 // A-half rows iA..iA+3
  const int iB   = iA + 8;                    // B-half rows

  const float* gxp = gridx + (size_t)b * WW + j;
  const float* gyp = gridy + (size_t)b * WW + j;

  // A-half grid loads + qsum offset: drain at barrier 1
  float gxvA[4], gyvA[4];
#pragma unroll
  for (int r = 0; r < 4; ++r) {
    gxvA[r] = gxp[(size_t)(iA + r) * WID];
    gyvA[r] = gyp[(size_t)(iA + r) * WID];
  }
  float offc = -DEF_OFF_F;   // hoisted: (gy + offy) - DEF_OFF == gy + offc
  if (FUSEY) {
    const int q = r0 >> 7;   // cross-quad offset, uniform per block
    const float* qs = qsum + (size_t)b * 4 * WID + j;
    for (int w = 0; w < q; ++w) offc += qs[(size_t)w * WID];
  }

  __syncthreads();  // barrier 1: phase-1 stage + A-grid ready (80 KB drain)

  // ---- phase-2 stage: LDS rows 24..31 (global r0+16 .. r0+23), 16 KB ----
  // Writes are address-disjoint from half-A's reads (ly<=23): safe to fly
  // under compute A; ordered before half-B's reads by barrier 2.
  {
    int chunk = 3072 + (int)threadIdx.x;      // 1 chunk per thread
    int lr = chunk >> 7;
    int c4 = (chunk & 127) << 2;
    int gr = r0 - 8 + lr;                     // r0+16 .. r0+23
    gr = gr > WID - 1 ? WID - 1 : gr;
    gl_lds16(ic + (size_t)gr * WID + c4, &tile[chunk << 2]);
  }
  // B-half grid loads: complete under compute A, drained at barrier 2
  float gxvB[4], gyvB[4];
#pragma unroll
  for (int r = 0; r < 4; ++r) {
    gxvB[r] = gxp[(size_t)(iB + r) * WID];
    gyvB[r] = gyp[(size_t)(iB + r) * WID];
  }

  float* ob = out + ((size_t)b * NC + c) * WW;

  auto pix = [&](int i, float gx, float gy) {
    if (FUSEY) {
      const float gyl = seqf(i);               // 1 cvt + 1 fma, no divide
      float d = (gy + offc) - gyl;
      d = fminf(fmaxf(d, -CLIP_F), CLIP_F);
      gy = fminf(fmaxf(d + gyl, -1.0f), 1.0f);
    }
    float x = (gx + 1.0f) * (0.5f * (float)(WID - 1));
    float y = (gy + 1.0f) * (0.5f * (float)(WID - 1));
    float x0f = floorf(x), y0f = floorf(y);
    int x0 = (int)x0f, y0 = (int)y0f;
    float wx1 = x - x0f;
    float wy1 = y - y0f;
    // +1 taps that would fall OOB have bilinear weight exactly 0
    int dx = x0 < WID - 1 ? 1 : 0;
    int dy = y0 < WID - 1 ? WID : 0;          // row step in floats
    int i00 = ((y0 - r0 + 8) << 9) + x0;

    float v00 = tile[i00];
    float v01 = tile[i00 + dx];
    float v10 = tile[i00 + dy];
    float v11 = tile[i00 + dy + dx];

    float top = v00 + wx1 * (v01 - v00);      // lerp form
    float bot = v10 + wx1 * (v11 - v10);
    ob[(size_t)i * WID + j] = top + wy1 * (bot - top);
  };

  // ---- compute half A (LDS rows 0..23 only) ----
#pragma unroll
  for (int r = 0; r < 4; ++r) pix(iA + r, gxvA[r], gyvA[r]);

  __syncthreads();  // barrier 2: phase-2 stage ready (mostly pre-drained)

  // ---- compute half B (LDS rows 8..31) ----
#pragma unroll
  for (int r = 0; r < 4; ++r) pix(iB + r, gxvB[r], gyvB[r]);
}

extern "C" void kernel_launch(void* const* d_in, const int* in_sizes, int n_in,
                              void* d_out, int out_size, void* d_ws, size_t ws_size,
                              hipStream_t stream) {
  const float* img = (const float*)d_in[0];
  const float* pg  = (const float*)d_in[1];
  float* out = (float*)d_out;

  float* gridx = (float*)d_ws;
  float* gridy = gridx + (size_t)NB * WW;

  const size_t grids_bytes = (size_t)2 * NB * WW * sizeof(float);
  const size_t qsum_bytes  = (size_t)NB * 4 * WID * sizeof(float); // 256 KB
  const bool ws_fits = (ws_size >= grids_bytes + qsum_bytes);
  float* qsum = ws_fits ? (float*)((char*)d_ws + grids_bytes)
                        : (float*)d_out;  // fallback scratch; needs ky2 pass

  double sigma = 5.0 * 0.15 + 0.35;
  double p0 = exp(-0.5 * (2.0 / sigma) * (2.0 / sigma));
  double p1 = exp(-0.5 * (1.0 / sigma) * (1.0 / sigma));
  double p2 = 1.0;
  double sum = 2.0 * p0 + 2.0 * p1 + p2;
  float kw0 = (float)(p0 / sum), kw1 = (float)(p1 / sum), kw2 = (float)(p2 / sum);

  grid_kernel<<<2048 + NB * 32, 512, 0, stream>>>(pg, gridx, gridy, qsum,
                                                  kw0, kw1, kw2);
  if (ws_fits) {
    sample_kernel<true><<<SAMP_BLOCKS, 1024, 0, stream>>>(img, gridx, gridy,
                                                          qsum, out);
  } else {
    ky2_kernel<<<NB * WID, 128, 0, stream>>>(gridy, qsum);
    sample_kernel<false><<<SAMP_BLOCKS, 1024, 0, stream>>>(img, gridx, gridy,
                                                           qsum, out);
  }
}